// Round 5
// baseline (592.993 us; speedup 1.0000x reference)
//
#include <hip/hip_runtime.h>

namespace {

constexpr int T_STEPS = 1024;
constexpr int BATCH   = 16;
constexpr int NNEUR   = 2048;
constexpr int MCOLS   = 512;
constexpr int BN      = BATCH * NNEUR;   // 32768

constexpr double DT_D   = 1e-7;
constexpr double TAU_D  = 1e-4;

constexpr float DT_F     = 1e-7f;
constexpr float CMEM_F   = 1e-12f;
constexpr float GLEAK_F  = 1e-9f;
constexpr float VTH_F    = 0.7f;             // VTH * GAIN
constexpr float REFRAC_F = 1e-6f;
constexpr float AINC_F   = 5e-11f;
constexpr float DECAY_F  = (float)(1.0 - DT_D / TAU_D);   // 0.999f
constexpr float VRESET_F = 0.0f;

// Reg-staged pipeline geometry: 256 blocks x 128 threads (2 waves), 1 neuron/thread.
constexpr int NPB     = 128;                  // neurons per block
constexpr int C_STEPS = 16;                   // timesteps per buffer
constexpr int NBUF    = T_STEPS / C_STEPS;    // 64
constexpr int NROWS   = 3 * C_STEPS;          // 48 rows x 128 floats (512 B) per buffer
constexpr int LPW     = 12;                   // dwordx4 loads per wave per buffer

} // namespace

// One LIF step, byte-identical numerics to the passing kernels.
#define LIF_STEP(ec, ic, vc, tidx)                                         \
    do {                                                                   \
        float t      = (float)(tidx) * DT_F;                               \
        bool  active = (t - ls) >= REFRAC_F;                               \
        float totI   = ((ec) - A) + (ic);                                  \
        float Vn     = (V + (DT_F * (totI - GLEAK_F * V)) / CMEM_F) + (vc);\
        float An     = A * DECAY_F;                                        \
        float V1     = active ? Vn : V;                                    \
        float A1     = active ? An : A;                                    \
        bool  spike  = active && (V1 >= VTH_F);                            \
        V  = spike ? VRESET_F : V1;                                        \
        A  = spike ? (A1 + AINC_F) : A1;                                   \
        ls = spike ? t : ls;                                               \
        count += spike ? 1 : 0;                                            \
    } while (0)

// 256 blocks x 2 waves. Plain global_load_dwordx4 -> register ring (depth 4)
// -> ds_write_b128 -> raw barrier -> compute. Counted vmcnt, never 0 in the
// main loop; lgkmcnt(0)+s_barrier only (no vmcnt drain at barriers).
__global__ __launch_bounds__(128, 1) void lif_sim_kernel(
    const float* __restrict__ ext,
    const float* __restrict__ inz,
    const float* __restrict__ vnz,
    float* __restrict__ rates)
{
    __shared__ float smem[4][NROWS][NPB];   // 4 slots x 24 KB = 96 KB

    const int tid  = threadIdx.x;
    const int lane = tid & 63;
    const int w    = tid >> 6;          // wave 0..1
    const int n0   = blockIdx.x * NPB;
    const int hi   = lane >> 5;         // which 512B row of the instr's pair
    const int nn   = (lane & 31) * 4;   // float index within the 128-float row

    // Each wave-instr i covers rows (w*12+i)*2 + {0,1}; row r = a*16 + tt.
    const float* pb[LPW];
    int row[LPW];
#pragma unroll
    for (int i = 0; i < LPW; ++i) {
        int r  = (w * LPW + i) * 2 + hi;
        row[i] = r;
        int a  = r >> 4;          // 0..2 array select
        int tt = r & 15;          // timestep within buffer
        const float* ba = (a == 0) ? ext : ((a == 1) ? inz : vnz);
        pb[i] = ba + (size_t)tt * BN + (n0 + nn);
    }

    float4 b0[LPW], b1[LPW], b2[LPW], b3[LPW];

#define ISSUE(J, B)                                                        \
    _Pragma("unroll")                                                      \
    for (int i = 0; i < LPW; ++i)                                          \
        B[i] = *(const float4*)(pb[i] + (size_t)(J) * (C_STEPS * BN));

    // prologue: fill the 4-deep register ring (48 loads/wave outstanding)
    ISSUE(0, b0) ISSUE(1, b1) ISSUE(2, b2) ISSUE(3, b3)

    float V = 0.0f, A = 0.0f, ls = -1e9f;
    int count = 0;

    // Per iteration K (slot = K%4, static via unroll):
    //  wait vmcnt(W)   -> buffer K's 12 loads landed (W = 12 * #future bufs)
    //  ds_write_b128   -> stage buffer K into LDS slot
    //  reissue K+4     -> into the same registers (WAR handled by compiler)
    //  lgkmcnt(0)+bar  -> writes visible to both waves; prior slot reads drained
    //  compute 16 LIF steps from LDS
#define PIPE_ITER(K, B, SLOT, WLIT, DOISS)                                 \
    do {                                                                   \
        asm volatile("s_waitcnt vmcnt(" #WLIT ")" ::: "memory");           \
        __builtin_amdgcn_sched_barrier(0);                                 \
        _Pragma("unroll")                                                  \
        for (int i = 0; i < LPW; ++i)                                      \
            *(float4*)&smem[SLOT][row[i]][nn] = B[i];                      \
        if (DOISS) { ISSUE((K) + 4, B) }                                   \
        asm volatile("s_waitcnt lgkmcnt(0)" ::: "memory");                 \
        __builtin_amdgcn_s_barrier();                                      \
        __builtin_amdgcn_sched_barrier(0);                                 \
        _Pragma("unroll")                                                  \
        for (int c = 0; c < C_STEPS; ++c) {                                \
            float ec = smem[SLOT][c][tid];                                 \
            float ic = smem[SLOT][C_STEPS + c][tid];                       \
            float vc = smem[SLOT][2 * C_STEPS + c][tid];                   \
            LIF_STEP(ec, ic, vc, (K) * C_STEPS + c);                       \
        }                                                                  \
    } while (0)

    for (int kb = 0; kb < NBUF - 4; kb += 4) {
        PIPE_ITER(kb + 0, b0, 0, 36, 1);
        PIPE_ITER(kb + 1, b1, 1, 36, 1);
        PIPE_ITER(kb + 2, b2, 2, 36, 1);
        PIPE_ITER(kb + 3, b3, 3, 36, 1);
    }
    // epilogue: drain 48 -> 36 -> 24 -> 12 -> 0 outstanding
    PIPE_ITER(NBUF - 4, b0, 0, 36, 0);
    PIPE_ITER(NBUF - 3, b1, 1, 24, 0);
    PIPE_ITER(NBUF - 2, b2, 2, 12, 0);
    PIPE_ITER(NBUF - 1, b3, 3, 0,  0);

#undef PIPE_ITER
#undef ISSUE

    rates[n0 + tid] = (float)count * (1.0f / 1024.0f);
}

// ---------------- readout: rates[16,2048] @ (Gn*0.1)[2048,512] ----------------
constexpr int KC   = 8;
constexpr int KCH  = NNEUR / KC;    // 256 k per chunk
constexpr int KSUB = 4;             // waves per block splitting the chunk
constexpr int KPT  = KCH / KSUB;    // 64 k per thread

__global__ __launch_bounds__(256) void readout_partial_kernel(
    const float* __restrict__ rates,
    const float* __restrict__ G,
    const float* __restrict__ cn,
    float* __restrict__ part)
{
    __shared__ float red[KSUB][64][BATCH + 1];

    const int tid = threadIdx.x;
    const int ml  = tid & 63;
    const int s   = tid >> 6;
    const int m   = blockIdx.x * 64 + ml;
    const int kc  = blockIdx.y;
    const int k0  = kc * KCH + s * KPT;

    float acc[BATCH];
#pragma unroll
    for (int b = 0; b < BATCH; ++b) acc[b] = 0.0f;

#pragma unroll 4
    for (int k = k0; k < k0 + KPT; ++k) {
        float g = G[(size_t)k * MCOLS + m];
        float c = cn[(size_t)k * MCOLS + m];
        float w = fmaxf(1e-8f, g * (1.0f + 0.1118f * c)) * 0.1f;  // Gn * READ_V
#pragma unroll
        for (int b = 0; b < BATCH; ++b) {
            acc[b] = fmaf(rates[b * NNEUR + k], w, acc[b]);
        }
    }

#pragma unroll
    for (int b = 0; b < BATCH; ++b) red[s][ml][b] = acc[b];
    __syncthreads();

    if (s == 0) {
#pragma unroll
        for (int b = 0; b < BATCH; ++b) {
            float v = ((red[0][ml][b] + red[1][ml][b]) + red[2][ml][b]) + red[3][ml][b];
            part[((size_t)kc * BATCH + b) * MCOLS + m] = v;
        }
    }
}

__global__ __launch_bounds__(256) void readout_reduce_kernel(
    const float* __restrict__ part,
    float* __restrict__ out)
{
    const int i = blockIdx.x * 256 + threadIdx.x;  // 0..8191 = b*512+m
    float s = 0.0f;
#pragma unroll
    for (int kc = 0; kc < KC; ++kc) {
        s += part[kc * (BATCH * MCOLS) + i];
    }
    out[i] = s;
}

extern "C" void kernel_launch(void* const* d_in, const int* in_sizes, int n_in,
                              void* d_out, int out_size, void* d_ws, size_t ws_size,
                              hipStream_t stream)
{
    const float* ext = (const float*)d_in[0];   // [T,B,N]
    const float* inz = (const float*)d_in[1];   // [T,B,N]
    const float* vnz = (const float*)d_in[2];   // [T,B,N]
    const float* G   = (const float*)d_in[3];   // [N,M]
    const float* cn  = (const float*)d_in[4];   // [N,M]
    float* out = (float*)d_out;                 // [B,M] = 8192

    float* rates = (float*)d_ws;                // 32768 floats
    float* part  = rates + BN;                  // 8*16*512 = 65536 floats

    lif_sim_kernel<<<BN / NPB, NPB, 0, stream>>>(ext, inz, vnz, rates);
    readout_partial_kernel<<<dim3(MCOLS / 64, KC), 256, 0, stream>>>(rates, G, cn, part);
    readout_reduce_kernel<<<(BATCH * MCOLS) / 256, 256, 0, stream>>>(part, out);
}

// Round 6
// 124.403 us; speedup vs baseline: 4.7667x; 4.7667x over previous
//
#include <hip/hip_runtime.h>

namespace {

constexpr int T_STEPS = 1024;
constexpr int BATCH   = 16;
constexpr int NNEUR   = 2048;
constexpr int MCOLS   = 512;
constexpr int BN      = BATCH * NNEUR;   // 32768

constexpr double DT_D   = 1e-7;
constexpr double TAU_D  = 1e-4;

constexpr float DT_F     = 1e-7f;
constexpr float CMEM_F   = 1e-12f;
constexpr float GLEAK_F  = 1e-9f;
constexpr float VTH_F    = 0.7f;             // VTH * GAIN
constexpr float REFRAC_F = 1e-6f;
constexpr float AINC_F   = 5e-11f;
constexpr float DECAY_F  = (float)(1.0 - DT_D / TAU_D);   // 0.999f
constexpr float VRESET_F = 0.0f;

// Producer/consumer geometry: 256 blocks x 384 threads.
// waves 0-1: compute (128 neurons, 1/thread). waves 2-5: loaders.
constexpr int NPB     = 128;                  // neurons per block
constexpr int C_STEPS = 8;                    // timesteps per buffer
constexpr int NBUF    = T_STEPS / C_STEPS;    // 128
constexpr int NROWS   = 3 * C_STEPS;          // 24 rows of 512B per buffer
constexpr int RPW     = 6;                    // rows per loader wave per buffer
constexpr int AHEAD   = 4;                    // loader register ring depth
constexpr int SLOT_F  = 3 * C_STEPS * NPB;    // floats per LDS slot (3072)

} // namespace

// One LIF step, byte-identical numerics to the passing kernels.
#define LIF_STEP(ec, ic, vc, tidx)                                         \
    do {                                                                   \
        float t      = (float)(tidx) * DT_F;                               \
        bool  active = (t - ls) >= REFRAC_F;                               \
        float totI   = ((ec) - A) + (ic);                                  \
        float Vn     = (V + (DT_F * (totI - GLEAK_F * V)) / CMEM_F) + (vc);\
        float An     = A * DECAY_F;                                        \
        float V1     = active ? Vn : V;                                    \
        float A1     = active ? An : A;                                    \
        bool  spike  = active && (V1 >= VTH_F);                            \
        V  = spike ? VRESET_F : V1;                                        \
        A  = spike ? (A1 + AINC_F) : A1;                                   \
        ls = spike ? t : ls;                                               \
        count += spike ? 1 : 0;                                            \
    } while (0)

__global__ __launch_bounds__(384, 1) void lif_sim_kernel(
    const float* __restrict__ ext,
    const float* __restrict__ inz,
    const float* __restrict__ vnz,
    float* __restrict__ rates)
{
    // 2-slot handoff buffer: [slot][array][t][neuron] = 2 x 12 KB
    __shared__ float slotmem[2][3][C_STEPS][NPB];

    const int tid  = threadIdx.x;
    const int lane = tid & 63;
    const int w    = tid >> 6;          // 0..5
    const int n0   = blockIdx.x * NPB;

    if (w >= 2) {
        // ---------------- loader waves (4) ----------------
        const int lw = w - 2;           // 0..3
        const float* pg[RPW];           // global row base (this wave's rows)
        float*       pl[RPW];           // LDS slot-0 destination
#pragma unroll
        for (int i = 0; i < RPW; ++i) {
            const int r  = lw * RPW + i;    // 0..23
            const int a  = r >> 3;          // array select
            const int tt = r & 7;           // timestep within buffer
            const float* ba = (a == 0) ? ext : ((a == 1) ? inz : vnz);
            pg[i] = ba + (size_t)tt * BN + (n0 + lane * 2);
            pl[i] = &slotmem[0][a][tt][lane * 2];
        }

        float2 rb0[RPW], rb1[RPW], rb2[RPW], rb3[RPW];

#define LISSUE(J, RB)                                                      \
        _Pragma("unroll")                                                  \
        for (int i = 0; i < RPW; ++i)                                      \
            RB[i] = *(const float2*)(pg[i] + (size_t)(J) * (C_STEPS * BN));

        // prologue: buffers 0..3 in flight (24 dwordx2 per wave)
        LISSUE(0, rb0) LISSUE(1, rb1) LISSUE(2, rb2) LISSUE(3, rb3)

        // Per iteration J (slot = J%2, reg-buf = J%4):
        //  vmcnt(W): buffer J's 6 loads landed (W = 6 * #future buffers)
        //  ds_write rows -> slot ; lgkmcnt(0) publishes (and frees regs)
        //  reissue J+4 into same regs ; raw barrier (never drains vmcnt)
#define LITER(J, RB, S, WLIT, DOISS)                                       \
        do {                                                               \
            asm volatile("s_waitcnt vmcnt(" #WLIT ")" ::: "memory");       \
            __builtin_amdgcn_sched_barrier(0);                             \
            _Pragma("unroll")                                              \
            for (int i = 0; i < RPW; ++i)                                  \
                *(float2*)(pl[i] + (S) * SLOT_F) = RB[i];                  \
            asm volatile("s_waitcnt lgkmcnt(0)" ::: "memory");             \
            __builtin_amdgcn_sched_barrier(0);                             \
            if (DOISS) { LISSUE((J) + AHEAD, RB) }                         \
            __builtin_amdgcn_sched_barrier(0);                             \
            __builtin_amdgcn_s_barrier();                                  \
            __builtin_amdgcn_sched_barrier(0);                             \
        } while (0)

        for (int jb = 0; jb < (NBUF / 4) - 1; ++jb) {
            LITER(jb * 4 + 0, rb0, 0, 18, 1);
            LITER(jb * 4 + 1, rb1, 1, 18, 1);
            LITER(jb * 4 + 2, rb2, 0, 18, 1);
            LITER(jb * 4 + 3, rb3, 1, 18, 1);
        }
        // epilogue: drain 24 -> 18 -> 12 -> 6 -> 0
        LITER(NBUF - 4, rb0, 0, 18, 0);
        LITER(NBUF - 3, rb1, 1, 12, 0);
        LITER(NBUF - 2, rb2, 0, 6,  0);
        LITER(NBUF - 1, rb3, 1, 0,  0);

#undef LITER
#undef LISSUE
    } else {
        // ---------------- compute waves (2): 1 neuron per thread ----------------
        float V = 0.0f, A = 0.0f, ls = -1e9f;
        int count = 0;

        for (int jb = 0; jb < NBUF / 4; ++jb) {
#pragma unroll
            for (int u = 0; u < 4; ++u) {
                __builtin_amdgcn_s_barrier();
                __builtin_amdgcn_sched_barrier(0);
                const int s = u & 1;
#pragma unroll
                for (int c = 0; c < C_STEPS; ++c) {
                    float ec = slotmem[s][0][c][tid];
                    float ic = slotmem[s][1][c][tid];
                    float vc = slotmem[s][2][c][tid];
                    LIF_STEP(ec, ic, vc, (jb * 4 + u) * C_STEPS + c);
                }
                __builtin_amdgcn_sched_barrier(0);   // keep reads inside window
            }
        }
        rates[n0 + tid] = (float)count * (1.0f / 1024.0f);
    }
}

// ---------------- readout: rates[16,2048] @ (Gn*0.1)[2048,512] ----------------
constexpr int KC   = 8;
constexpr int KCH  = NNEUR / KC;    // 256 k per chunk
constexpr int KSUB = 4;             // waves per block splitting the chunk
constexpr int KPT  = KCH / KSUB;    // 64 k per thread

__global__ __launch_bounds__(256) void readout_partial_kernel(
    const float* __restrict__ rates,
    const float* __restrict__ G,
    const float* __restrict__ cn,
    float* __restrict__ part)
{
    __shared__ float red[KSUB][64][BATCH + 1];

    const int tid = threadIdx.x;
    const int ml  = tid & 63;
    const int s   = tid >> 6;
    const int m   = blockIdx.x * 64 + ml;
    const int kc  = blockIdx.y;
    const int k0  = kc * KCH + s * KPT;

    float acc[BATCH];
#pragma unroll
    for (int b = 0; b < BATCH; ++b) acc[b] = 0.0f;

#pragma unroll 4
    for (int k = k0; k < k0 + KPT; ++k) {
        float g = G[(size_t)k * MCOLS + m];
        float c = cn[(size_t)k * MCOLS + m];
        float w = fmaxf(1e-8f, g * (1.0f + 0.1118f * c)) * 0.1f;  // Gn * READ_V
#pragma unroll
        for (int b = 0; b < BATCH; ++b) {
            acc[b] = fmaf(rates[b * NNEUR + k], w, acc[b]);
        }
    }

#pragma unroll
    for (int b = 0; b < BATCH; ++b) red[s][ml][b] = acc[b];
    __syncthreads();

    if (s == 0) {
#pragma unroll
        for (int b = 0; b < BATCH; ++b) {
            float v = ((red[0][ml][b] + red[1][ml][b]) + red[2][ml][b]) + red[3][ml][b];
            part[((size_t)kc * BATCH + b) * MCOLS + m] = v;
        }
    }
}

__global__ __launch_bounds__(256) void readout_reduce_kernel(
    const float* __restrict__ part,
    float* __restrict__ out)
{
    const int i = blockIdx.x * 256 + threadIdx.x;  // 0..8191 = b*512+m
    float s = 0.0f;
#pragma unroll
    for (int kc = 0; kc < KC; ++kc) {
        s += part[kc * (BATCH * MCOLS) + i];
    }
    out[i] = s;
}

extern "C" void kernel_launch(void* const* d_in, const int* in_sizes, int n_in,
                              void* d_out, int out_size, void* d_ws, size_t ws_size,
                              hipStream_t stream)
{
    const float* ext = (const float*)d_in[0];   // [T,B,N]
    const float* inz = (const float*)d_in[1];   // [T,B,N]
    const float* vnz = (const float*)d_in[2];   // [T,B,N]
    const float* G   = (const float*)d_in[3];   // [N,M]
    const float* cn  = (const float*)d_in[4];   // [N,M]
    float* out = (float*)d_out;                 // [B,M] = 8192

    float* rates = (float*)d_ws;                // 32768 floats
    float* part  = rates + BN;                  // 8*16*512 = 65536 floats

    lif_sim_kernel<<<BN / NPB, 384, 0, stream>>>(ext, inz, vnz, rates);
    readout_partial_kernel<<<dim3(MCOLS / 64, KC), 256, 0, stream>>>(rates, G, cn, part);
    readout_reduce_kernel<<<(BATCH * MCOLS) / 256, 256, 0, stream>>>(part, out);
}